// Round 5
// baseline (292.740 us; speedup 1.0000x reference)
//
#include <hip/hip_runtime.h>
#include <math.h>

#define NN 100000       // N_NODES
#define NE 800000       // N_EDGES
#define DN 64           // D_NODE
#define DE 4            // D_EDGE
#define HH 128          // H_MSG == H_UPD
#define NT 64           // nodes per block (k_xproj MFMA)
#define NT2 64          // nodes per block (k_update, MFMA)
#define SCAN_B 256
#define NBLK_SCAN ((NN + SCAN_B - 1) / SCAN_B)   // 391
#define EPAD 16         // padding entries on es/ef4 so es prefetch never branches

using bf16x8 = __attribute__((ext_vector_type(8))) short;
using f32x4  = __attribute__((ext_vector_type(4))) float;

// bf16 helpers (manual, RNE)
__device__ __forceinline__ unsigned short f2bf(float f) {
    unsigned int u = __float_as_uint(f);
    unsigned int r = (u + 0x7fffu + ((u >> 16) & 1u)) >> 16;
    return (unsigned short)r;
}
__device__ __forceinline__ float bf2f(unsigned short h) {
    return __uint_as_float(((unsigned int)h) << 16);
}
__device__ __forceinline__ float2 bfpair2f(unsigned int v) {
    return make_float2(__uint_as_float(v << 16),
                       __uint_as_float(v & 0xffff0000u));
}
// wave-uniform -> SGPR helpers
__device__ __forceinline__ int rfl_i(int v) { return __builtin_amdgcn_readfirstlane(v); }
__device__ __forceinline__ float rfl_f(float v) {
    return __uint_as_float((unsigned)__builtin_amdgcn_readfirstlane((int)__float_as_uint(v)));
}

// ---------------------------------------------------------------------------
// Kernel 1 (MFMA): [XA(bf16) | XB(f32)] = x @ [W1[0:64,:] | W1[64:128,:]]
// 64 nodes/block, 4 waves; K=64 (2 kb), N=256 (16 n-tiles).  (R1 form.)
// ---------------------------------------------------------------------------
__global__ __launch_bounds__(256) void k_xproj(const float* __restrict__ x,
                                               const unsigned short* __restrict__ Wpx,
                                               unsigned short* __restrict__ XAb,
                                               float* __restrict__ XB) {
    __shared__ unsigned short sA[8 * 64 * 8];   // 8 KB; [Q=kb*4+quad][m][j]
    const int n0 = blockIdx.x * NT;
    const int t  = threadIdx.x;
    const int w    = t >> 6;
    const int l    = t & 63;
    const int quad = l >> 4;
    const int l16  = l & 15;

    // stage x (64 nodes x 64 k) bf16 into A-frag layout
#pragma unroll
    for (int it = 0; it < 4; ++it) {
        const int flat = t + it * 256;    // node*16 + c
        const int node = flat >> 4;
        const int c    = flat & 15;
        const int gn   = n0 + node;
        float4 v = make_float4(0.f, 0.f, 0.f, 0.f);
        if (gn < NN) v = *(const float4*)(x + (size_t)gn * DN + c * 4);
        const int k = c * 4, Q = k >> 3, j0 = k & 7;
        uint2 pk;
        pk.x = (unsigned)f2bf(v.x) | ((unsigned)f2bf(v.y) << 16);
        pk.y = (unsigned)f2bf(v.z) | ((unsigned)f2bf(v.w) << 16);
        *(uint2*)(&sA[(Q * 64 + node) * 8 + j0]) = pk;
    }
    __syncthreads();

    const int mrow = w * 16 + l16;
    f32x4 acc[16];
#pragma unroll
    for (int nt = 0; nt < 16; ++nt) { acc[nt][0] = 0.f; acc[nt][1] = 0.f; acc[nt][2] = 0.f; acc[nt][3] = 0.f; }

#pragma unroll
    for (int kb = 0; kb < 2; ++kb) {
        bf16x8 a = *(const bf16x8*)(const void*)(&sA[((kb * 4 + quad) * 64 + mrow) * 8]);
#pragma unroll
        for (int nt = 0; nt < 16; ++nt) {
            bf16x8 b = *(const bf16x8*)(const void*)(Wpx + ((size_t)(nt * 2 + kb) * 64 + l) * 8);
            acc[nt] = __builtin_amdgcn_mfma_f32_16x16x32_bf16(a, b, acc[nt], 0, 0, 0);
        }
    }
    // store: tiles 0..7 -> XA (bf16), tiles 8..15 -> XB (f32)
#pragma unroll
    for (int nt = 0; nt < 8; ++nt) {
        const int col = nt * 16 + l16;
#pragma unroll
        for (int r = 0; r < 4; ++r) {
            const int gn = n0 + w * 16 + quad * 4 + r;
            if (gn < NN) XAb[(size_t)gn * HH + col] = f2bf(acc[nt][r]);
        }
    }
#pragma unroll
    for (int nt = 8; nt < 16; ++nt) {
        const int col = (nt - 8) * 16 + l16;
#pragma unroll
        for (int r = 0; r < 4; ++r) {
            const int gn = n0 + w * 16 + quad * 4 + r;
            if (gn < NN) XB[(size_t)gn * HH + col] = acc[nt][r];
        }
    }
}

// ---------------------------------------------------------------------------
// Fold kernel: Wc = W2 @ U1[64:128,:];  cvec = b2 @ U1[64:128,:]
// ---------------------------------------------------------------------------
__global__ __launch_bounds__(256) void k_fold(const float* __restrict__ W2,
                                              const float* __restrict__ U1,
                                              const float* __restrict__ b2,
                                              float* __restrict__ Wc,
                                              float* __restrict__ cvec) {
    const int idx = blockIdx.x * 256 + threadIdx.x;
    const float* u1b = U1 + (size_t)DN * HH;
    if (blockIdx.x < 64) {
        const int r = idx >> 7;
        const int c = idx & 127;
        float acc = 0.f;
#pragma unroll 8
        for (int j = 0; j < DN; ++j)
            acc = fmaf(W2[(size_t)r * DN + j], u1b[(size_t)j * HH + c], acc);
        Wc[(size_t)r * HH + c] = acc;
    } else if (threadIdx.x < HH) {
        const int c = threadIdx.x;
        float acc = 0.f;
#pragma unroll 8
        for (int j = 0; j < DN; ++j)
            acc = fmaf(b2[j], u1b[(size_t)j * HH + c], acc);
        cvec[c] = acc;
    }
}

// ---------------------------------------------------------------------------
// Pack kernel: weights -> bf16 B-fragment layout for mfma_f32_16x16x32_bf16.
// B-frag: lane l holds B[k = kb*32 + (l>>4)*8 + j][n = ntile*16 + (l&15)].
// ---------------------------------------------------------------------------
__global__ __launch_bounds__(256) void k_pack(const float* __restrict__ U1,
                                              const float* __restrict__ Wc,
                                              const float* __restrict__ U2,
                                              const float* __restrict__ W1,
                                              unsigned short* __restrict__ Wpa,
                                              unsigned short* __restrict__ Wpb,
                                              unsigned short* __restrict__ Wpx) {
    const int tid = blockIdx.x * 256 + threadIdx.x;
    if (tid < 3072) {
        const int l  = tid & 63;
        const int kb = (tid >> 6) % 6;
        const int n  = tid / 384;
        const int kbase = kb * 32 + (l >> 4) * 8;
        const int col   = n * 16 + (l & 15);
        unsigned short tmp[8];
#pragma unroll
        for (int j = 0; j < 8; ++j) {
            const int k = kbase + j;
            const float v = (k < DN) ? U1[(size_t)k * HH + col]
                                     : Wc[(size_t)(k - DN) * HH + col];
            tmp[j] = f2bf(v);
        }
        *(uint4*)(Wpa + (size_t)tid * 8) = *(const uint4*)tmp;
    } else if (tid < 4096) {
        const int t2 = tid - 3072;
        const int l  = t2 & 63;
        const int kb = (t2 >> 6) & 3;
        const int n2 = t2 >> 8;
        const int kbase = kb * 32 + (l >> 4) * 8;
        const int col   = n2 * 16 + (l & 15);
        unsigned short tmp[8];
#pragma unroll
        for (int j = 0; j < 8; ++j) tmp[j] = f2bf(U2[(size_t)(kbase + j) * DN + col]);
        *(uint4*)(Wpb + (size_t)t2 * 8) = *(const uint4*)tmp;
    } else if (tid < 6144) {
        const int t3 = tid - 4096;
        const int l  = t3 & 63;
        const int kb = (t3 >> 6) & 1;
        const int nt = t3 >> 7;               // 0..15
        const int kbase = kb * 32 + (l >> 4) * 8;
        const int row0  = (nt < 8) ? 0 : DN;  // XA from rows 0..63, XB from 64..127
        const int col   = ((nt & 7) * 16) + (l & 15);
        unsigned short tmp[8];
#pragma unroll
        for (int j = 0; j < 8; ++j)
            tmp[j] = f2bf(W1[(size_t)(row0 + kbase + j) * HH + col]);
        *(uint4*)(Wpx + (size_t)t3 * 8) = *(const uint4*)tmp;
    }
}

// ---------------------------------------------------------------------------
// Counting sort by destination
// ---------------------------------------------------------------------------
__global__ __launch_bounds__(256) void k_hist(const int* __restrict__ ei,
                                              int* __restrict__ cnt,
                                              int* __restrict__ es) {
    const int e = blockIdx.x * 256 + threadIdx.x;
    if (e < NE) atomicAdd(&cnt[ei[NE + e]], 1);
    if (blockIdx.x == 0 && threadIdx.x < EPAD) es[NE + threadIdx.x] = 0;  // zero pad
}

__global__ __launch_bounds__(SCAN_B) void k_scan_a(const int* __restrict__ cnt,
                                                   int* __restrict__ pos,
                                                   int* __restrict__ bsum) {
    __shared__ int sh[SCAN_B];
    const int n = blockIdx.x * SCAN_B + threadIdx.x;
    const int c = (n < NN) ? cnt[n] : 0;
    sh[threadIdx.x] = c;
    __syncthreads();
    int v = c;
#pragma unroll
    for (int off = 1; off < SCAN_B; off <<= 1) {
        int add = (threadIdx.x >= off) ? sh[threadIdx.x - off] : 0;
        __syncthreads();
        v += add;
        sh[threadIdx.x] = v;
        __syncthreads();
    }
    if (n < NN) pos[n] = v - c;
    if (threadIdx.x == SCAN_B - 1) bsum[blockIdx.x] = v;
}

__global__ __launch_bounds__(512) void k_scan_b(int* __restrict__ bsum) {
    __shared__ int sh[512];
    const int i = threadIdx.x;
    const int c = (i < NBLK_SCAN) ? bsum[i] : 0;
    sh[i] = c;
    __syncthreads();
    int v = c;
#pragma unroll
    for (int off = 1; off < 512; off <<= 1) {
        int add = (i >= off) ? sh[i - off] : 0;
        __syncthreads();
        v += add;
        sh[i] = v;
        __syncthreads();
    }
    if (i < NBLK_SCAN) bsum[i] = v - c;
}

// ---------------------------------------------------------------------------
// R13 scatter: 4 consecutive edges per thread. int4 src/dst loads (coalesced
// 16B/lane), 4 INDEPENDENT atomicAdd round-trips in flight (the atomic return
// is the critical path; one-edge-per-thread exposed its full latency), then
// contiguous float4 ef loads and fire-and-forget scattered stores.
// es stores BYTE offsets (s * HH * 2) so k_agg gather addr is saddr+voffset.
// ---------------------------------------------------------------------------
__global__ __launch_bounds__(256) void k_scatter(const int* __restrict__ ei,
                                                 const float* __restrict__ ef,
                                                 int* __restrict__ pos,
                                                 const int* __restrict__ boff,
                                                 int* __restrict__ es,
                                                 float4* __restrict__ ef4) {
    const int e0 = (blockIdx.x * 256 + threadIdx.x) * 4;
    if (e0 >= NE) return;                      // NE % 4 == 0 -> full quads only
    const int4 s4 = *(const int4*)(ei + e0);
    const int4 d4 = *(const int4*)(ei + NE + e0);
    // 4 independent atomic round-trips (overlapped by the HW)
    const int r0 = atomicAdd(&pos[d4.x], 1);
    const int r1 = atomicAdd(&pos[d4.y], 1);
    const int r2 = atomicAdd(&pos[d4.z], 1);
    const int r3 = atomicAdd(&pos[d4.w], 1);
    const int sl0 = r0 + boff[d4.x >> 8];
    const int sl1 = r1 + boff[d4.y >> 8];
    const int sl2 = r2 + boff[d4.z >> 8];
    const int sl3 = r3 + boff[d4.w >> 8];
    const float4 f0 = *(const float4*)(ef + (size_t)(e0 + 0) * 4);
    const float4 f1 = *(const float4*)(ef + (size_t)(e0 + 1) * 4);
    const float4 f2 = *(const float4*)(ef + (size_t)(e0 + 2) * 4);
    const float4 f3 = *(const float4*)(ef + (size_t)(e0 + 3) * 4);
    es[sl0] = s4.x * (HH * 2);
    es[sl1] = s4.y * (HH * 2);
    es[sl2] = s4.z * (HH * 2);
    es[sl3] = s4.w * (HH * 2);
    ef4[sl0] = make_float4(log1pf(f0.x), log1pf(f0.y), log1pf(f0.z), log1pf(f0.w));
    ef4[sl1] = make_float4(log1pf(f1.x), log1pf(f1.y), log1pf(f1.z), log1pf(f1.w));
    ef4[sl2] = make_float4(log1pf(f2.x), log1pf(f2.y), log1pf(f2.z), log1pf(f2.w));
    ef4[sl3] = make_float4(log1pf(f3.x), log1pf(f3.y), log1pf(f3.z), log1pf(f3.w));
}

// ---------------------------------------------------------------------------
// Segmented reduce, one wave per node.  (R12 form, unchanged: scalarized
// control flow, depth-4 ping-pong pipeline, SGPR-base gathers.)
// ---------------------------------------------------------------------------
#define EDGE_COMPUTE_S(fx, fy, fz, fw, aa)                       \
    {                                                            \
        const float2 av = bfpair2f(aa);                          \
        float h0 = av.x + base0;                                 \
        float h1 = av.y + base1;                                 \
        h0 = fmaf(fx, wv0.x, h0); h0 = fmaf(fy, wv1.x, h0);      \
        h0 = fmaf(fz, wv2.x, h0); h0 = fmaf(fw, wv3.x, h0);      \
        h1 = fmaf(fx, wv0.y, h1); h1 = fmaf(fy, wv1.y, h1);      \
        h1 = fmaf(fz, wv2.y, h1); h1 = fmaf(fw, wv3.y, h1);      \
        acc0 += fmaxf(h0, 0.f);                                  \
        acc1 += fmaxf(h1, 0.f);                                  \
    }

#define LOAD_EF_S(PX, idx)                                       \
    { const float4 _t = ef4[idx];                                \
      PX##x = rfl_f(_t.x); PX##y = rfl_f(_t.y);                  \
      PX##z = rfl_f(_t.z); PX##w = rfl_f(_t.w); }

__global__ __launch_bounds__(256) void k_agg(const int* __restrict__ es,
                                             const float4* __restrict__ ef4,
                                             const int* __restrict__ pos,
                                             const int* __restrict__ boff,
                                             const int* __restrict__ cnt,
                                             const unsigned short* __restrict__ XAb,
                                             const float* __restrict__ XB,
                                             const float* __restrict__ W1,
                                             const float* __restrict__ b1,
                                             unsigned short* __restrict__ Haggb,
                                             float* __restrict__ deg) {
    const int lane = threadIdx.x & 63;
    const int du = rfl_i(blockIdx.x * 4 + (threadIdx.x >> 6));   // SGPR node id
    if (du >= NN) return;
    const int c     = rfl_i(cnt[du]);
    const int end   = rfl_i(pos[du]) + rfl_i(boff[du >> 8]);
    const int start = end - c;
    const int j0    = lane * 2;
    const unsigned jb = (unsigned)(lane * 4);   // byte offset of this lane's pair

    const float* we = W1 + 128 * HH;
    const float2 xb = *(const float2*)(XB + (size_t)du * HH + j0);
    const float2 bb = *(const float2*)(b1 + j0);
    const float base0 = xb.x + bb.x;
    const float base1 = xb.y + bb.y;
    const float2 wv0 = *(const float2*)(we + 0 * HH + j0);
    const float2 wv1 = *(const float2*)(we + 1 * HH + j0);
    const float2 wv2 = *(const float2*)(we + 2 * HH + j0);
    const float2 wv3 = *(const float2*)(we + 3 * HH + j0);

    float acc0 = 0.f, acc1 = 0.f;
    if (c > 0) {
        const char* XAc = (const char*)XAb;
        // es byte-offsets for edges start..start+3 (SGPR)
        int eA0 = rfl_i(es[start + 0]), eA1 = rfl_i(es[start + 1]);
        int eB0 = rfl_i(es[start + 2]), eB1 = rfl_i(es[start + 3]);
        // gathers (VGPR) + broadcast edge features (SGPR)
        unsigned aA0 = 0u, aA1 = 0u, aB0 = 0u, aB1 = 0u;
        float fA0x = 0.f, fA0y = 0.f, fA0z = 0.f, fA0w = 0.f;
        float fA1x = 0.f, fA1y = 0.f, fA1z = 0.f, fA1w = 0.f;
        float fB0x = 0.f, fB0y = 0.f, fB0z = 0.f, fB0w = 0.f;
        float fB1x = 0.f, fB1y = 0.f, fB1z = 0.f, fB1w = 0.f;
        aA0 = *(const unsigned*)(XAc + (unsigned)eA0 + jb);
        LOAD_EF_S(fA0, start + 0);
        if (c > 1) { aA1 = *(const unsigned*)(XAc + (unsigned)eA1 + jb); LOAD_EF_S(fA1, start + 1); }
        if (c > 2) { aB0 = *(const unsigned*)(XAc + (unsigned)eB0 + jb); LOAD_EF_S(fB0, start + 2); }
        if (c > 3) { aB1 = *(const unsigned*)(XAc + (unsigned)eB1 + jb); LOAD_EF_S(fB1, start + 3); }
        // refill es one group ahead (edges start+4..start+7; pad-safe)
        eA0 = rfl_i(es[start + 4]); eA1 = rfl_i(es[start + 5]);
        eB0 = rfl_i(es[start + 6]); eB1 = rfl_i(es[start + 7]);

        int k = start;
        while (true) {
            // ---- phase A: compute edges k, k+1
            EDGE_COMPUTE_S(fA0x, fA0y, fA0z, fA0w, aA0);
            if (k + 1 < end) EDGE_COMPUTE_S(fA1x, fA1y, fA1z, fA1w, aA1);
            if (k + 2 >= end) break;
            // prefetch edges k+4, k+5 (addresses arrived one iteration ago)
            if (k + 4 < end) { aA0 = *(const unsigned*)(XAc + (unsigned)eA0 + jb); LOAD_EF_S(fA0, k + 4); }
            if (k + 5 < end) { aA1 = *(const unsigned*)(XAc + (unsigned)eA1 + jb); LOAD_EF_S(fA1, k + 5); }
            eA0 = rfl_i(es[k + 8]); eA1 = rfl_i(es[k + 9]);        // pad-safe
            // ---- phase B: compute edges k+2, k+3
            EDGE_COMPUTE_S(fB0x, fB0y, fB0z, fB0w, aB0);
            if (k + 3 < end) EDGE_COMPUTE_S(fB1x, fB1y, fB1z, fB1w, aB1);
            if (k + 4 >= end) break;
            if (k + 6 < end) { aB0 = *(const unsigned*)(XAc + (unsigned)eB0 + jb); LOAD_EF_S(fB0, k + 6); }
            if (k + 7 < end) { aB1 = *(const unsigned*)(XAc + (unsigned)eB1 + jb); LOAD_EF_S(fB1, k + 7); }
            eB0 = rfl_i(es[k + 10]); eB1 = rfl_i(es[k + 11]);      // pad-safe
            k += 4;
        }
    }
    const unsigned int p = (unsigned)f2bf(acc0) | ((unsigned)f2bf(acc1) << 16);
    *(unsigned int*)(Haggb + (size_t)du * HH + j0) = p;
    if (lane == 0) deg[du] = (float)c;
}

// ---------------------------------------------------------------------------
// Fallback edge kernel (atomic path) — writes f32 Hagg
// ---------------------------------------------------------------------------
__global__ __launch_bounds__(256) void k_edge_atomic(const int* __restrict__ ei,
                                                     const float* __restrict__ ef,
                                                     const float* __restrict__ W1,
                                                     const float* __restrict__ b1,
                                                     const unsigned short* __restrict__ XAb,
                                                     const float* __restrict__ XB,
                                                     float* __restrict__ Hagg,
                                                     float* __restrict__ deg) {
    const int wave = threadIdx.x >> 6;
    const int lane = threadIdx.x & 63;
    const long e = (long)blockIdx.x * 4 + wave;
    if (e >= NE) return;
    const int s = ei[e];
    const int d = ei[NE + e];

    float t = 0.f;
    if (lane < DE) t = log1pf(ef[e * DE + lane]);
    const float l0 = __shfl(t, 0);
    const float l1 = __shfl(t, 1);
    const float l2 = __shfl(t, 2);
    const float l3 = __shfl(t, 3);

    const float* we = W1 + 128 * HH;
    const size_t sb = (size_t)s * HH;
    const size_t db = (size_t)d * HH;
#pragma unroll
    for (int r = 0; r < 2; ++r) {
        const int j = lane + r * 64;
        float h = bf2f(XAb[sb + j]) + XB[db + j] + b1[j];
        h = fmaf(l0, we[0 * HH + j], h);
        h = fmaf(l1, we[1 * HH + j], h);
        h = fmaf(l2, we[2 * HH + j], h);
        h = fmaf(l3, we[3 * HH + j], h);
        h = fmaxf(h, 0.f);
        atomicAdd(&Hagg[db + j], h);
    }
    if (lane == 0) atomicAdd(&deg[d], 1.f);
}

// ---------------------------------------------------------------------------
// Kernel 3 (MFMA): 64 nodes/block, 4 waves. Hagg read as bf16 (sorted path)
// or f32 (fallback).  (R1 form.)
// ---------------------------------------------------------------------------
__global__ __launch_bounds__(256) void k_update(const float* __restrict__ x,
                                                const void* __restrict__ HaggV,
                                                const int hbf16,
                                                const float* __restrict__ deg,
                                                const unsigned short* __restrict__ Wpa,
                                                const unsigned short* __restrict__ Wpb,
                                                const float* __restrict__ cvec,
                                                const float* __restrict__ bu1,
                                                const float* __restrict__ bu2,
                                                float* __restrict__ out) {
    __shared__ unsigned short sA[6 * 4 * 64 * 8];   // 24 KB
    __shared__ float sdeg[NT2];
    const int n0 = blockIdx.x * NT2;
    const int t  = threadIdx.x;
    const int w    = t >> 6;
    const int l    = t & 63;
    const int quad = l >> 4;
    const int l16  = l & 15;

#pragma unroll
    for (int it = 0; it < 4; ++it) {
        const int flat = t + it * 256;
        const int node = flat >> 4;
        const int c    = flat & 15;
        const int gn   = n0 + node;
        float4 v = make_float4(0.f, 0.f, 0.f, 0.f);
        if (gn < NN) v = *(const float4*)(x + (size_t)gn * DN + c * 4);
        const int k = c * 4, Q = k >> 3, j0 = k & 7;
        uint2 pk;
        pk.x = (unsigned)f2bf(v.x) | ((unsigned)f2bf(v.y) << 16);
        pk.y = (unsigned)f2bf(v.z) | ((unsigned)f2bf(v.w) << 16);
        *(uint2*)(&sA[(Q * 64 + node) * 8 + j0]) = pk;
    }
    if (hbf16) {
        const unsigned short* Hb = (const unsigned short*)HaggV;
#pragma unroll
        for (int it = 0; it < 4; ++it) {
            const int flat = t + it * 256;        // 64 nodes x 16 chunks of 8 ch
            const int node = flat >> 4;
            const int c8   = flat & 15;
            const int gn   = n0 + node;
            uint4 v = make_uint4(0u, 0u, 0u, 0u);
            if (gn < NN) v = *(const uint4*)(Hb + (size_t)gn * HH + c8 * 8);
            const int Q = 8 + c8;                 // k = DN + c8*8
            *(uint4*)(&sA[(Q * 64 + node) * 8]) = v;
        }
    } else {
        const float* Hagg = (const float*)HaggV;
#pragma unroll
        for (int it = 0; it < 8; ++it) {
            const int flat = t + it * 256;
            const int node = flat >> 5;
            const int c    = flat & 31;
            const int gn   = n0 + node;
            float4 v = make_float4(0.f, 0.f, 0.f, 0.f);
            if (gn < NN) v = *(const float4*)(Hagg + (size_t)gn * HH + c * 4);
            const int k = DN + c * 4, Q = k >> 3, j0 = k & 7;
            uint2 pk;
            pk.x = (unsigned)f2bf(v.x) | ((unsigned)f2bf(v.y) << 16);
            pk.y = (unsigned)f2bf(v.z) | ((unsigned)f2bf(v.w) << 16);
            *(uint2*)(&sA[(Q * 64 + node) * 8 + j0]) = pk;
        }
    }
    if (t < NT2) sdeg[t] = (n0 + t < NN) ? deg[n0 + t] : 0.f;
    __syncthreads();

    f32x4 acc[8];
#pragma unroll
    for (int n = 0; n < 8; ++n) {
        const int col = n * 16 + l16;
        const float bv = bu1[col];
        const float cv = cvec[col];
#pragma unroll
        for (int r = 0; r < 4; ++r)
            acc[n][r] = fmaf(sdeg[w * 16 + quad * 4 + r], cv, bv);
    }
    const int mrow = w * 16 + l16;
#pragma unroll
    for (int kb = 0; kb < 6; ++kb) {
        bf16x8 a = *(const bf16x8*)(const void*)(&sA[((kb * 4 + quad) * 64 + mrow) * 8]);
#pragma unroll
        for (int n = 0; n < 8; ++n) {
            bf16x8 b = *(const bf16x8*)(const void*)(Wpa + ((size_t)(n * 6 + kb) * 64 + l) * 8);
            acc[n] = __builtin_amdgcn_mfma_f32_16x16x32_bf16(a, b, acc[n], 0, 0, 0);
        }
    }
    __syncthreads();

#pragma unroll
    for (int n = 0; n < 8; ++n) {
        const int col = n * 16 + l16;
        const int Q = col >> 3;
        const int j = col & 7;
#pragma unroll
        for (int r = 0; r < 4; ++r) {
            const int m = w * 16 + quad * 4 + r;
            sA[(Q * 64 + m) * 8 + j] = f2bf(fmaxf(acc[n][r], 0.f));
        }
    }
    __syncthreads();

    f32x4 acc2[4];
#pragma unroll
    for (int n2 = 0; n2 < 4; ++n2) {
        const float bv = bu2[n2 * 16 + l16];
        acc2[n2][0] = bv; acc2[n2][1] = bv; acc2[n2][2] = bv; acc2[n2][3] = bv;
    }
#pragma unroll
    for (int kb = 0; kb < 4; ++kb) {
        bf16x8 a = *(const bf16x8*)(const void*)(&sA[((kb * 4 + quad) * 64 + mrow) * 8]);
#pragma unroll
        for (int n2 = 0; n2 < 4; ++n2) {
            bf16x8 b = *(const bf16x8*)(const void*)(Wpb + ((size_t)(n2 * 4 + kb) * 64 + l) * 8);
            acc2[n2] = __builtin_amdgcn_mfma_f32_16x16x32_bf16(a, b, acc2[n2], 0, 0, 0);
        }
    }
#pragma unroll
    for (int n2 = 0; n2 < 4; ++n2) {
        const int col = n2 * 16 + l16;
#pragma unroll
        for (int r = 0; r < 4; ++r) {
            const int gn = n0 + w * 16 + quad * 4 + r;
            if (gn < NN) out[(size_t)gn * DN + col] = acc2[n2][r];
        }
    }
}

extern "C" void kernel_launch(void* const* d_in, const int* in_sizes, int n_in,
                              void* d_out, int out_size, void* d_ws, size_t ws_size,
                              hipStream_t stream) {
    const float* x   = (const float*)d_in[0];
    const int*   ei  = (const int*)d_in[1];
    const float* ef  = (const float*)d_in[2];
    const float* W1  = (const float*)d_in[3];
    const float* b1  = (const float*)d_in[4];
    const float* W2  = (const float*)d_in[5];
    const float* b2  = (const float*)d_in[6];
    const float* U1  = (const float*)d_in[7];
    const float* bu1 = (const float*)d_in[8];
    const float* U2  = (const float*)d_in[9];
    const float* bu2 = (const float*)d_in[10];
    float* out = (float*)d_out;

    unsigned short* XAb = (unsigned short*)d_ws;       // [NN,128] bf16
    float* XB   = (float*)(XAb + (size_t)NN * HH);     // [NN,128] f32
    float* Hagg = XB + (size_t)NN * HH;                // [NN,128] f32 (fallback) / bf16 alias (sorted)
    float* deg  = Hagg + (size_t)NN * HH;              // [NN]
    float* Wc   = deg + NN;                            // [128,128]
    float* cvec = Wc + (size_t)HH * HH;                // [128]
    unsigned short* Wpa = (unsigned short*)(cvec + HH);// [8*6*64*8]
    unsigned short* Wpb = Wpa + 8 * 6 * 64 * 8;        // [4*4*64*8]
    unsigned short* Wpx = Wpb + 4 * 4 * 64 * 8;        // [16*2*64*8]
    int*   cnt  = (int*)(Wpx + 16 * 2 * 64 * 8);       // [NN]
    int*   pos  = cnt + NN;                            // [NN]
    int*   boff = pos + NN;                            // [1024]
    int*   es   = boff + 1024;                         // [NE+EPAD]
    float4* ef4 = (float4*)(es + NE + EPAD);           // [NE+EPAD]
    const size_t need = (size_t)((char*)(ef4 + NE + EPAD) - (char*)d_ws);

    unsigned short* Haggb = (unsigned short*)Hagg;     // bf16 alias (sorted path)

    const int nblk  = (NN + NT - 1) / NT;
    const int nblk2 = (NN + NT2 - 1) / NT2;

    k_fold<<<65, 256, 0, stream>>>(W2, U1, b2, Wc, cvec);
    k_pack<<<24, 256, 0, stream>>>(U1, Wc, U2, W1, Wpa, Wpb, Wpx);

    if (ws_size >= need) {
        hipMemsetAsync(cnt, 0, (size_t)NN * sizeof(int), stream);
        k_xproj<<<nblk, 256, 0, stream>>>(x, Wpx, XAb, XB);
        k_hist<<<(NE + 255) / 256, 256, 0, stream>>>(ei, cnt, es);
        k_scan_a<<<NBLK_SCAN, SCAN_B, 0, stream>>>(cnt, pos, boff);
        k_scan_b<<<1, 512, 0, stream>>>(boff);
        k_scatter<<<(NE / 4 + 255) / 256, 256, 0, stream>>>(ei, ef, pos, boff, es, ef4);
        k_agg<<<(NN + 3) / 4, 256, 0, stream>>>(es, ef4, pos, boff, cnt, XAb, XB, W1, b1, Haggb, deg);
        k_update<<<nblk2, 256, 0, stream>>>(x, (const void*)Haggb, 1, deg, Wpa, Wpb, cvec, bu1, bu2, out);
    } else {
        hipMemsetAsync(Hagg, 0, ((size_t)NN * HH + NN) * sizeof(float), stream);
        k_xproj<<<nblk, 256, 0, stream>>>(x, Wpx, XAb, XB);
        k_edge_atomic<<<NE / 4, 256, 0, stream>>>(ei, ef, W1, b1, XAb, XB, Hagg, deg);
        k_update<<<nblk2, 256, 0, stream>>>(x, (const void*)Hagg, 0, deg, Wpa, Wpb, cvec, bu1, bu2, out);
    }
}

// Round 6
// 265.377 us; speedup vs baseline: 1.1031x; 1.1031x over previous
//
#include <hip/hip_runtime.h>
#include <math.h>

#define NN 100000       // N_NODES
#define NE 800000       // N_EDGES
#define DN 64           // D_NODE
#define DE 4            // D_EDGE
#define HH 128          // H_MSG == H_UPD
#define NT 64           // nodes per block (k_xproj MFMA)
#define NT2 64          // nodes per block (k_update, MFMA)
#define SCAN_B 256
#define NBLK_SCAN ((NN + SCAN_B - 1) / SCAN_B)   // 391
#define EPAD 16         // padding entries on es/ef4 so es prefetch never branches

using bf16x8 = __attribute__((ext_vector_type(8))) short;
using f32x4  = __attribute__((ext_vector_type(4))) float;

// bf16 helpers (manual, RNE)
__device__ __forceinline__ unsigned short f2bf(float f) {
    unsigned int u = __float_as_uint(f);
    unsigned int r = (u + 0x7fffu + ((u >> 16) & 1u)) >> 16;
    return (unsigned short)r;
}
__device__ __forceinline__ float bf2f(unsigned short h) {
    return __uint_as_float(((unsigned int)h) << 16);
}
__device__ __forceinline__ float2 bfpair2f(unsigned int v) {
    return make_float2(__uint_as_float(v << 16),
                       __uint_as_float(v & 0xffff0000u));
}
// wave-uniform -> SGPR helpers
__device__ __forceinline__ int rfl_i(int v) { return __builtin_amdgcn_readfirstlane(v); }
__device__ __forceinline__ float rfl_f(float v) {
    return __uint_as_float((unsigned)__builtin_amdgcn_readfirstlane((int)__float_as_uint(v)));
}

// ---------------------------------------------------------------------------
// Kernel 1 (MFMA): [XA(bf16) | XB(f32)] = x @ [W1[0:64,:] | W1[64:128,:]]
// 64 nodes/block, 4 waves; K=64 (2 kb), N=256 (16 n-tiles).  (R1 form.)
// ---------------------------------------------------------------------------
__global__ __launch_bounds__(256) void k_xproj(const float* __restrict__ x,
                                               const unsigned short* __restrict__ Wpx,
                                               unsigned short* __restrict__ XAb,
                                               float* __restrict__ XB) {
    __shared__ unsigned short sA[8 * 64 * 8];   // 8 KB; [Q=kb*4+quad][m][j]
    const int n0 = blockIdx.x * NT;
    const int t  = threadIdx.x;
    const int w    = t >> 6;
    const int l    = t & 63;
    const int quad = l >> 4;
    const int l16  = l & 15;

    // stage x (64 nodes x 64 k) bf16 into A-frag layout
#pragma unroll
    for (int it = 0; it < 4; ++it) {
        const int flat = t + it * 256;    // node*16 + c
        const int node = flat >> 4;
        const int c    = flat & 15;
        const int gn   = n0 + node;
        float4 v = make_float4(0.f, 0.f, 0.f, 0.f);
        if (gn < NN) v = *(const float4*)(x + (size_t)gn * DN + c * 4);
        const int k = c * 4, Q = k >> 3, j0 = k & 7;
        uint2 pk;
        pk.x = (unsigned)f2bf(v.x) | ((unsigned)f2bf(v.y) << 16);
        pk.y = (unsigned)f2bf(v.z) | ((unsigned)f2bf(v.w) << 16);
        *(uint2*)(&sA[(Q * 64 + node) * 8 + j0]) = pk;
    }
    __syncthreads();

    const int mrow = w * 16 + l16;
    f32x4 acc[16];
#pragma unroll
    for (int nt = 0; nt < 16; ++nt) { acc[nt][0] = 0.f; acc[nt][1] = 0.f; acc[nt][2] = 0.f; acc[nt][3] = 0.f; }

#pragma unroll
    for (int kb = 0; kb < 2; ++kb) {
        bf16x8 a = *(const bf16x8*)(const void*)(&sA[((kb * 4 + quad) * 64 + mrow) * 8]);
#pragma unroll
        for (int nt = 0; nt < 16; ++nt) {
            bf16x8 b = *(const bf16x8*)(const void*)(Wpx + ((size_t)(nt * 2 + kb) * 64 + l) * 8);
            acc[nt] = __builtin_amdgcn_mfma_f32_16x16x32_bf16(a, b, acc[nt], 0, 0, 0);
        }
    }
    // store: tiles 0..7 -> XA (bf16), tiles 8..15 -> XB (f32)
#pragma unroll
    for (int nt = 0; nt < 8; ++nt) {
        const int col = nt * 16 + l16;
#pragma unroll
        for (int r = 0; r < 4; ++r) {
            const int gn = n0 + w * 16 + quad * 4 + r;
            if (gn < NN) XAb[(size_t)gn * HH + col] = f2bf(acc[nt][r]);
        }
    }
#pragma unroll
    for (int nt = 8; nt < 16; ++nt) {
        const int col = (nt - 8) * 16 + l16;
#pragma unroll
        for (int r = 0; r < 4; ++r) {
            const int gn = n0 + w * 16 + quad * 4 + r;
            if (gn < NN) XB[(size_t)gn * HH + col] = acc[nt][r];
        }
    }
}

// ---------------------------------------------------------------------------
// Fold kernel: Wc = W2 @ U1[64:128,:];  cvec = b2 @ U1[64:128,:]
// ---------------------------------------------------------------------------
__global__ __launch_bounds__(256) void k_fold(const float* __restrict__ W2,
                                              const float* __restrict__ U1,
                                              const float* __restrict__ b2,
                                              float* __restrict__ Wc,
                                              float* __restrict__ cvec) {
    const int idx = blockIdx.x * 256 + threadIdx.x;
    const float* u1b = U1 + (size_t)DN * HH;
    if (blockIdx.x < 64) {
        const int r = idx >> 7;
        const int c = idx & 127;
        float acc = 0.f;
#pragma unroll 8
        for (int j = 0; j < DN; ++j)
            acc = fmaf(W2[(size_t)r * DN + j], u1b[(size_t)j * HH + c], acc);
        Wc[(size_t)r * HH + c] = acc;
    } else if (threadIdx.x < HH) {
        const int c = threadIdx.x;
        float acc = 0.f;
#pragma unroll 8
        for (int j = 0; j < DN; ++j)
            acc = fmaf(b2[j], u1b[(size_t)j * HH + c], acc);
        cvec[c] = acc;
    }
}

// ---------------------------------------------------------------------------
// Pack kernel: weights -> bf16 B-fragment layout for mfma_f32_16x16x32_bf16.
// B-frag: lane l holds B[k = kb*32 + (l>>4)*8 + j][n = ntile*16 + (l&15)].
// ---------------------------------------------------------------------------
__global__ __launch_bounds__(256) void k_pack(const float* __restrict__ U1,
                                              const float* __restrict__ Wc,
                                              const float* __restrict__ U2,
                                              const float* __restrict__ W1,
                                              unsigned short* __restrict__ Wpa,
                                              unsigned short* __restrict__ Wpb,
                                              unsigned short* __restrict__ Wpx) {
    const int tid = blockIdx.x * 256 + threadIdx.x;
    if (tid < 3072) {
        const int l  = tid & 63;
        const int kb = (tid >> 6) % 6;
        const int n  = tid / 384;
        const int kbase = kb * 32 + (l >> 4) * 8;
        const int col   = n * 16 + (l & 15);
        unsigned short tmp[8];
#pragma unroll
        for (int j = 0; j < 8; ++j) {
            const int k = kbase + j;
            const float v = (k < DN) ? U1[(size_t)k * HH + col]
                                     : Wc[(size_t)(k - DN) * HH + col];
            tmp[j] = f2bf(v);
        }
        *(uint4*)(Wpa + (size_t)tid * 8) = *(const uint4*)tmp;
    } else if (tid < 4096) {
        const int t2 = tid - 3072;
        const int l  = t2 & 63;
        const int kb = (t2 >> 6) & 3;
        const int n2 = t2 >> 8;
        const int kbase = kb * 32 + (l >> 4) * 8;
        const int col   = n2 * 16 + (l & 15);
        unsigned short tmp[8];
#pragma unroll
        for (int j = 0; j < 8; ++j) tmp[j] = f2bf(U2[(size_t)(kbase + j) * DN + col]);
        *(uint4*)(Wpb + (size_t)t2 * 8) = *(const uint4*)tmp;
    } else if (tid < 6144) {
        const int t3 = tid - 4096;
        const int l  = t3 & 63;
        const int kb = (t3 >> 6) & 1;
        const int nt = t3 >> 7;               // 0..15
        const int kbase = kb * 32 + (l >> 4) * 8;
        const int row0  = (nt < 8) ? 0 : DN;  // XA from rows 0..63, XB from 64..127
        const int col   = ((nt & 7) * 16) + (l & 15);
        unsigned short tmp[8];
#pragma unroll
        for (int j = 0; j < 8; ++j)
            tmp[j] = f2bf(W1[(size_t)(row0 + kbase + j) * HH + col]);
        *(uint4*)(Wpx + (size_t)t3 * 8) = *(const uint4*)tmp;
    }
}

// ---------------------------------------------------------------------------
// R14: rank pass. ONE atomic per edge serves both the histogram (cnt) and
// the stable within-destination rank (returned value). k_scatter then needs
// no atomics at all. rank fits ushort (max degree << 64k for random graphs).
// ---------------------------------------------------------------------------
__global__ __launch_bounds__(256) void k_rank(const int* __restrict__ ei,
                                              int* __restrict__ cnt,
                                              unsigned short* __restrict__ rank,
                                              int* __restrict__ es) {
    const int e = blockIdx.x * 256 + threadIdx.x;
    if (e < NE) {
        const int d = ei[NE + e];
        rank[e] = (unsigned short)atomicAdd(&cnt[d], 1);
    }
    if (blockIdx.x == 0 && threadIdx.x < EPAD) es[NE + threadIdx.x] = 0;  // zero pad
}

__global__ __launch_bounds__(SCAN_B) void k_scan_a(const int* __restrict__ cnt,
                                                   int* __restrict__ pos,
                                                   int* __restrict__ bsum) {
    __shared__ int sh[SCAN_B];
    const int n = blockIdx.x * SCAN_B + threadIdx.x;
    const int c = (n < NN) ? cnt[n] : 0;
    sh[threadIdx.x] = c;
    __syncthreads();
    int v = c;
#pragma unroll
    for (int off = 1; off < SCAN_B; off <<= 1) {
        int add = (threadIdx.x >= off) ? sh[threadIdx.x - off] : 0;
        __syncthreads();
        v += add;
        sh[threadIdx.x] = v;
        __syncthreads();
    }
    if (n < NN) pos[n] = v - c;
    if (threadIdx.x == SCAN_B - 1) bsum[blockIdx.x] = v;
}

__global__ __launch_bounds__(512) void k_scan_b(int* __restrict__ bsum) {
    __shared__ int sh[512];
    const int i = threadIdx.x;
    const int c = (i < NBLK_SCAN) ? bsum[i] : 0;
    sh[i] = c;
    __syncthreads();
    int v = c;
#pragma unroll
    for (int off = 1; off < 512; off <<= 1) {
        int add = (i >= off) ? sh[i - off] : 0;
        __syncthreads();
        v += add;
        sh[i] = v;
        __syncthreads();
    }
    if (i < NBLK_SCAN) bsum[i] = v - c;
}

// ---------------------------------------------------------------------------
// R14 scatter: ATOMIC-FREE. slot = pos[d] + boff[d>>8] + rank[e].
// Pure streaming: coalesced ei/rank/ef loads, one L2-resident pos gather,
// fire-and-forget scattered stores. es stores BYTE offsets (s * HH * 2).
// ---------------------------------------------------------------------------
__global__ __launch_bounds__(256) void k_scatter(const int* __restrict__ ei,
                                                 const float* __restrict__ ef,
                                                 const int* __restrict__ pos,
                                                 const int* __restrict__ boff,
                                                 const unsigned short* __restrict__ rank,
                                                 int* __restrict__ es,
                                                 float4* __restrict__ ef4) {
    const int e = blockIdx.x * 256 + threadIdx.x;
    if (e >= NE) return;
    const int s = ei[e];
    const int d = ei[NE + e];
    const int slot = pos[d] + boff[d >> 8] + (int)rank[e];
    es[slot] = s * (HH * 2);
    ef4[slot] = make_float4(log1pf(ef[e * 4 + 0]), log1pf(ef[e * 4 + 1]),
                            log1pf(ef[e * 4 + 2]), log1pf(ef[e * 4 + 3]));
}

// ---------------------------------------------------------------------------
// Segmented reduce, one wave per node.  (R12 form; start/end now computed
// from unmutated pos[]: start = pos+boff, end = start+c.)
// ---------------------------------------------------------------------------
#define EDGE_COMPUTE_S(fx, fy, fz, fw, aa)                       \
    {                                                            \
        const float2 av = bfpair2f(aa);                          \
        float h0 = av.x + base0;                                 \
        float h1 = av.y + base1;                                 \
        h0 = fmaf(fx, wv0.x, h0); h0 = fmaf(fy, wv1.x, h0);      \
        h0 = fmaf(fz, wv2.x, h0); h0 = fmaf(fw, wv3.x, h0);      \
        h1 = fmaf(fx, wv0.y, h1); h1 = fmaf(fy, wv1.y, h1);      \
        h1 = fmaf(fz, wv2.y, h1); h1 = fmaf(fw, wv3.y, h1);      \
        acc0 += fmaxf(h0, 0.f);                                  \
        acc1 += fmaxf(h1, 0.f);                                  \
    }

#define LOAD_EF_S(PX, idx)                                       \
    { const float4 _t = ef4[idx];                                \
      PX##x = rfl_f(_t.x); PX##y = rfl_f(_t.y);                  \
      PX##z = rfl_f(_t.z); PX##w = rfl_f(_t.w); }

__global__ __launch_bounds__(256) void k_agg(const int* __restrict__ es,
                                             const float4* __restrict__ ef4,
                                             const int* __restrict__ pos,
                                             const int* __restrict__ boff,
                                             const int* __restrict__ cnt,
                                             const unsigned short* __restrict__ XAb,
                                             const float* __restrict__ XB,
                                             const float* __restrict__ W1,
                                             const float* __restrict__ b1,
                                             unsigned short* __restrict__ Haggb,
                                             float* __restrict__ deg) {
    const int lane = threadIdx.x & 63;
    const int du = rfl_i(blockIdx.x * 4 + (threadIdx.x >> 6));   // SGPR node id
    if (du >= NN) return;
    const int c     = rfl_i(cnt[du]);
    const int start = rfl_i(pos[du]) + rfl_i(boff[du >> 8]);
    const int end   = start + c;
    const int j0    = lane * 2;
    const unsigned jb = (unsigned)(lane * 4);   // byte offset of this lane's pair

    const float* we = W1 + 128 * HH;
    const float2 xb = *(const float2*)(XB + (size_t)du * HH + j0);
    const float2 bb = *(const float2*)(b1 + j0);
    const float base0 = xb.x + bb.x;
    const float base1 = xb.y + bb.y;
    const float2 wv0 = *(const float2*)(we + 0 * HH + j0);
    const float2 wv1 = *(const float2*)(we + 1 * HH + j0);
    const float2 wv2 = *(const float2*)(we + 2 * HH + j0);
    const float2 wv3 = *(const float2*)(we + 3 * HH + j0);

    float acc0 = 0.f, acc1 = 0.f;
    if (c > 0) {
        const char* XAc = (const char*)XAb;
        // es byte-offsets for edges start..start+3 (SGPR)
        int eA0 = rfl_i(es[start + 0]), eA1 = rfl_i(es[start + 1]);
        int eB0 = rfl_i(es[start + 2]), eB1 = rfl_i(es[start + 3]);
        // gathers (VGPR) + broadcast edge features (SGPR)
        unsigned aA0 = 0u, aA1 = 0u, aB0 = 0u, aB1 = 0u;
        float fA0x = 0.f, fA0y = 0.f, fA0z = 0.f, fA0w = 0.f;
        float fA1x = 0.f, fA1y = 0.f, fA1z = 0.f, fA1w = 0.f;
        float fB0x = 0.f, fB0y = 0.f, fB0z = 0.f, fB0w = 0.f;
        float fB1x = 0.f, fB1y = 0.f, fB1z = 0.f, fB1w = 0.f;
        aA0 = *(const unsigned*)(XAc + (unsigned)eA0 + jb);
        LOAD_EF_S(fA0, start + 0);
        if (c > 1) { aA1 = *(const unsigned*)(XAc + (unsigned)eA1 + jb); LOAD_EF_S(fA1, start + 1); }
        if (c > 2) { aB0 = *(const unsigned*)(XAc + (unsigned)eB0 + jb); LOAD_EF_S(fB0, start + 2); }
        if (c > 3) { aB1 = *(const unsigned*)(XAc + (unsigned)eB1 + jb); LOAD_EF_S(fB1, start + 3); }
        // refill es one group ahead (edges start+4..start+7; pad-safe)
        eA0 = rfl_i(es[start + 4]); eA1 = rfl_i(es[start + 5]);
        eB0 = rfl_i(es[start + 6]); eB1 = rfl_i(es[start + 7]);

        int k = start;
        while (true) {
            // ---- phase A: compute edges k, k+1
            EDGE_COMPUTE_S(fA0x, fA0y, fA0z, fA0w, aA0);
            if (k + 1 < end) EDGE_COMPUTE_S(fA1x, fA1y, fA1z, fA1w, aA1);
            if (k + 2 >= end) break;
            // prefetch edges k+4, k+5 (addresses arrived one iteration ago)
            if (k + 4 < end) { aA0 = *(const unsigned*)(XAc + (unsigned)eA0 + jb); LOAD_EF_S(fA0, k + 4); }
            if (k + 5 < end) { aA1 = *(const unsigned*)(XAc + (unsigned)eA1 + jb); LOAD_EF_S(fA1, k + 5); }
            eA0 = rfl_i(es[k + 8]); eA1 = rfl_i(es[k + 9]);        // pad-safe
            // ---- phase B: compute edges k+2, k+3
            EDGE_COMPUTE_S(fB0x, fB0y, fB0z, fB0w, aB0);
            if (k + 3 < end) EDGE_COMPUTE_S(fB1x, fB1y, fB1z, fB1w, aB1);
            if (k + 4 >= end) break;
            if (k + 6 < end) { aB0 = *(const unsigned*)(XAc + (unsigned)eB0 + jb); LOAD_EF_S(fB0, k + 6); }
            if (k + 7 < end) { aB1 = *(const unsigned*)(XAc + (unsigned)eB1 + jb); LOAD_EF_S(fB1, k + 7); }
            eB0 = rfl_i(es[k + 10]); eB1 = rfl_i(es[k + 11]);      // pad-safe
            k += 4;
        }
    }
    const unsigned int p = (unsigned)f2bf(acc0) | ((unsigned)f2bf(acc1) << 16);
    *(unsigned int*)(Haggb + (size_t)du * HH + j0) = p;
    if (lane == 0) deg[du] = (float)c;
}

// ---------------------------------------------------------------------------
// Fallback edge kernel (atomic path) — writes f32 Hagg
// ---------------------------------------------------------------------------
__global__ __launch_bounds__(256) void k_edge_atomic(const int* __restrict__ ei,
                                                     const float* __restrict__ ef,
                                                     const float* __restrict__ W1,
                                                     const float* __restrict__ b1,
                                                     const unsigned short* __restrict__ XAb,
                                                     const float* __restrict__ XB,
                                                     float* __restrict__ Hagg,
                                                     float* __restrict__ deg) {
    const int wave = threadIdx.x >> 6;
    const int lane = threadIdx.x & 63;
    const long e = (long)blockIdx.x * 4 + wave;
    if (e >= NE) return;
    const int s = ei[e];
    const int d = ei[NE + e];

    float t = 0.f;
    if (lane < DE) t = log1pf(ef[e * DE + lane]);
    const float l0 = __shfl(t, 0);
    const float l1 = __shfl(t, 1);
    const float l2 = __shfl(t, 2);
    const float l3 = __shfl(t, 3);

    const float* we = W1 + 128 * HH;
    const size_t sb = (size_t)s * HH;
    const size_t db = (size_t)d * HH;
#pragma unroll
    for (int r = 0; r < 2; ++r) {
        const int j = lane + r * 64;
        float h = bf2f(XAb[sb + j]) + XB[db + j] + b1[j];
        h = fmaf(l0, we[0 * HH + j], h);
        h = fmaf(l1, we[1 * HH + j], h);
        h = fmaf(l2, we[2 * HH + j], h);
        h = fmaf(l3, we[3 * HH + j], h);
        h = fmaxf(h, 0.f);
        atomicAdd(&Hagg[db + j], h);
    }
    if (lane == 0) atomicAdd(&deg[d], 1.f);
}

// ---------------------------------------------------------------------------
// Kernel 3 (MFMA): 64 nodes/block, 4 waves. Hagg read as bf16 (sorted path)
// or f32 (fallback).  (R1 form.)
// ---------------------------------------------------------------------------
__global__ __launch_bounds__(256) void k_update(const float* __restrict__ x,
                                                const void* __restrict__ HaggV,
                                                const int hbf16,
                                                const float* __restrict__ deg,
                                                const unsigned short* __restrict__ Wpa,
                                                const unsigned short* __restrict__ Wpb,
                                                const float* __restrict__ cvec,
                                                const float* __restrict__ bu1,
                                                const float* __restrict__ bu2,
                                                float* __restrict__ out) {
    __shared__ unsigned short sA[6 * 4 * 64 * 8];   // 24 KB
    __shared__ float sdeg[NT2];
    const int n0 = blockIdx.x * NT2;
    const int t  = threadIdx.x;
    const int w    = t >> 6;
    const int l    = t & 63;
    const int quad = l >> 4;
    const int l16  = l & 15;

#pragma unroll
    for (int it = 0; it < 4; ++it) {
        const int flat = t + it * 256;
        const int node = flat >> 4;
        const int c    = flat & 15;
        const int gn   = n0 + node;
        float4 v = make_float4(0.f, 0.f, 0.f, 0.f);
        if (gn < NN) v = *(const float4*)(x + (size_t)gn * DN + c * 4);
        const int k = c * 4, Q = k >> 3, j0 = k & 7;
        uint2 pk;
        pk.x = (unsigned)f2bf(v.x) | ((unsigned)f2bf(v.y) << 16);
        pk.y = (unsigned)f2bf(v.z) | ((unsigned)f2bf(v.w) << 16);
        *(uint2*)(&sA[(Q * 64 + node) * 8 + j0]) = pk;
    }
    if (hbf16) {
        const unsigned short* Hb = (const unsigned short*)HaggV;
#pragma unroll
        for (int it = 0; it < 4; ++it) {
            const int flat = t + it * 256;        // 64 nodes x 16 chunks of 8 ch
            const int node = flat >> 4;
            const int c8   = flat & 15;
            const int gn   = n0 + node;
            uint4 v = make_uint4(0u, 0u, 0u, 0u);
            if (gn < NN) v = *(const uint4*)(Hb + (size_t)gn * HH + c8 * 8);
            const int Q = 8 + c8;                 // k = DN + c8*8
            *(uint4*)(&sA[(Q * 64 + node) * 8]) = v;
        }
    } else {
        const float* Hagg = (const float*)HaggV;
#pragma unroll
        for (int it = 0; it < 8; ++it) {
            const int flat = t + it * 256;
            const int node = flat >> 5;
            const int c    = flat & 31;
            const int gn   = n0 + node;
            float4 v = make_float4(0.f, 0.f, 0.f, 0.f);
            if (gn < NN) v = *(const float4*)(Hagg + (size_t)gn * HH + c * 4);
            const int k = DN + c * 4, Q = k >> 3, j0 = k & 7;
            uint2 pk;
            pk.x = (unsigned)f2bf(v.x) | ((unsigned)f2bf(v.y) << 16);
            pk.y = (unsigned)f2bf(v.z) | ((unsigned)f2bf(v.w) << 16);
            *(uint2*)(&sA[(Q * 64 + node) * 8 + j0]) = pk;
        }
    }
    if (t < NT2) sdeg[t] = (n0 + t < NN) ? deg[n0 + t] : 0.f;
    __syncthreads();

    f32x4 acc[8];
#pragma unroll
    for (int n = 0; n < 8; ++n) {
        const int col = n * 16 + l16;
        const float bv = bu1[col];
        const float cv = cvec[col];
#pragma unroll
        for (int r = 0; r < 4; ++r)
            acc[n][r] = fmaf(sdeg[w * 16 + quad * 4 + r], cv, bv);
    }
    const int mrow = w * 16 + l16;
#pragma unroll
    for (int kb = 0; kb < 6; ++kb) {
        bf16x8 a = *(const bf16x8*)(const void*)(&sA[((kb * 4 + quad) * 64 + mrow) * 8]);
#pragma unroll
        for (int n = 0; n < 8; ++n) {
            bf16x8 b = *(const bf16x8*)(const void*)(Wpa + ((size_t)(n * 6 + kb) * 64 + l) * 8);
            acc[n] = __builtin_amdgcn_mfma_f32_16x16x32_bf16(a, b, acc[n], 0, 0, 0);
        }
    }
    __syncthreads();

#pragma unroll
    for (int n = 0; n < 8; ++n) {
        const int col = n * 16 + l16;
        const int Q = col >> 3;
        const int j = col & 7;
#pragma unroll
        for (int r = 0; r < 4; ++r) {
            const int m = w * 16 + quad * 4 + r;
            sA[(Q * 64 + m) * 8 + j] = f2bf(fmaxf(acc[n][r], 0.f));
        }
    }
    __syncthreads();

    f32x4 acc2[4];
#pragma unroll
    for (int n2 = 0; n2 < 4; ++n2) {
        const float bv = bu2[n2 * 16 + l16];
        acc2[n2][0] = bv; acc2[n2][1] = bv; acc2[n2][2] = bv; acc2[n2][3] = bv;
    }
#pragma unroll
    for (int kb = 0; kb < 4; ++kb) {
        bf16x8 a = *(const bf16x8*)(const void*)(&sA[((kb * 4 + quad) * 64 + mrow) * 8]);
#pragma unroll
        for (int n2 = 0; n2 < 4; ++n2) {
            bf16x8 b = *(const bf16x8*)(const void*)(Wpb + ((size_t)(n2 * 4 + kb) * 64 + l) * 8);
            acc2[n2] = __builtin_amdgcn_mfma_f32_16x16x32_bf16(a, b, acc2[n2], 0, 0, 0);
        }
    }
#pragma unroll
    for (int n2 = 0; n2 < 4; ++n2) {
        const int col = n2 * 16 + l16;
#pragma unroll
        for (int r = 0; r < 4; ++r) {
            const int gn = n0 + w * 16 + quad * 4 + r;
            if (gn < NN) out[(size_t)gn * DN + col] = acc2[n2][r];
        }
    }
}

extern "C" void kernel_launch(void* const* d_in, const int* in_sizes, int n_in,
                              void* d_out, int out_size, void* d_ws, size_t ws_size,
                              hipStream_t stream) {
    const float* x   = (const float*)d_in[0];
    const int*   ei  = (const int*)d_in[1];
    const float* ef  = (const float*)d_in[2];
    const float* W1  = (const float*)d_in[3];
    const float* b1  = (const float*)d_in[4];
    const float* W2  = (const float*)d_in[5];
    const float* b2  = (const float*)d_in[6];
    const float* U1  = (const float*)d_in[7];
    const float* bu1 = (const float*)d_in[8];
    const float* U2  = (const float*)d_in[9];
    const float* bu2 = (const float*)d_in[10];
    float* out = (float*)d_out;

    unsigned short* XAb = (unsigned short*)d_ws;       // [NN,128] bf16
    float* XB   = (float*)(XAb + (size_t)NN * HH);     // [NN,128] f32
    float* Hagg = XB + (size_t)NN * HH;                // [NN,128] f32 (fallback) / bf16 alias (sorted)
    float* deg  = Hagg + (size_t)NN * HH;              // [NN]
    float* Wc   = deg + NN;                            // [128,128]
    float* cvec = Wc + (size_t)HH * HH;                // [128]
    unsigned short* Wpa = (unsigned short*)(cvec + HH);// [8*6*64*8]
    unsigned short* Wpb = Wpa + 8 * 6 * 64 * 8;        // [4*4*64*8]
    unsigned short* Wpx = Wpb + 4 * 4 * 64 * 8;        // [16*2*64*8]
    int*   cnt  = (int*)(Wpx + 16 * 2 * 64 * 8);       // [NN]
    int*   pos  = cnt + NN;                            // [NN]
    int*   boff = pos + NN;                            // [1024]
    int*   es   = boff + 1024;                         // [NE+EPAD]
    float4* ef4 = (float4*)(es + NE + EPAD);           // [NE+EPAD]
    unsigned short* rank = (unsigned short*)(ef4 + NE + EPAD);  // [NE]
    const size_t need = (size_t)((char*)(rank + NE) - (char*)d_ws);

    unsigned short* Haggb = (unsigned short*)Hagg;     // bf16 alias (sorted path)

    const int nblk  = (NN + NT - 1) / NT;
    const int nblk2 = (NN + NT2 - 1) / NT2;

    k_fold<<<65, 256, 0, stream>>>(W2, U1, b2, Wc, cvec);
    k_pack<<<24, 256, 0, stream>>>(U1, Wc, U2, W1, Wpa, Wpb, Wpx);

    if (ws_size >= need) {
        hipMemsetAsync(cnt, 0, (size_t)NN * sizeof(int), stream);
        k_xproj<<<nblk, 256, 0, stream>>>(x, Wpx, XAb, XB);
        k_rank<<<(NE + 255) / 256, 256, 0, stream>>>(ei, cnt, rank, es);
        k_scan_a<<<NBLK_SCAN, SCAN_B, 0, stream>>>(cnt, pos, boff);
        k_scan_b<<<1, 512, 0, stream>>>(boff);
        k_scatter<<<(NE + 255) / 256, 256, 0, stream>>>(ei, ef, pos, boff, rank, es, ef4);
        k_agg<<<(NN + 3) / 4, 256, 0, stream>>>(es, ef4, pos, boff, cnt, XAb, XB, W1, b1, Haggb, deg);
        k_update<<<nblk2, 256, 0, stream>>>(x, (const void*)Haggb, 1, deg, Wpa, Wpb, cvec, bu1, bu2, out);
    } else {
        hipMemsetAsync(Hagg, 0, ((size_t)NN * HH + NN) * sizeof(float), stream);
        k_xproj<<<nblk, 256, 0, stream>>>(x, Wpx, XAb, XB);
        k_edge_atomic<<<NE / 4, 256, 0, stream>>>(ei, ef, W1, b1, XAb, XB, Hagg, deg);
        k_update<<<nblk2, 256, 0, stream>>>(x, (const void*)Hagg, 0, deg, Wpa, Wpb, cvec, bu1, bu2, out);
    }
}